// Round 1
// baseline (4707.002 us; speedup 1.0000x reference)
//
#include <hip/hip_runtime.h>
#include <hip/hip_bf16.h>

#define BB 256
#define CC 1024
#define NP 25
#define EPS 1e-5f

// ---------------------------------------------------------------- utils

__device__ __forceinline__ void head_entry(int j, int* pp, int* ww)
{
  int cnt = 0;
  for (int y1 = 0; y1 < 5; y1++)
    for (int x1 = 0; x1 < 5; x1++) {
      int p = y1 * 5 + x1;
      int y2 = y1 + 2, x2 = x1 + 2;
      if (y2 == 2 || y2 == 3)
        for (int s = 0; s < 3; s++) { if (y2 + s + 1 > 6) break; if (cnt == j) { *pp = p; *ww = 0 + s; return; } cnt++; }
      if (y1 == 3 || y1 == 4)
        for (int s = 0; s < 3; s++) { if (y1 - (s + 1) < 0) break; if (cnt == j) { *pp = p; *ww = 3 + s; return; } cnt++; }
      if (x2 == 2 || x2 == 3)
        for (int s = 0; s < 3; s++) { if (x2 + s + 1 > 6) break; if (cnt == j) { *pp = p; *ww = 6 + s; return; } cnt++; }
      if (x1 == 3 || x1 == 4)
        for (int s = 0; s < 3; s++) { if (x1 - (s + 1) < 0) break; if (cnt == j) { *pp = p; *ww = 9 + s; return; } cnt++; }
    }
}

// ------------------------------------------------- layer-1 stats from x

// per-(c,y,x) batch sums: pos = c*49 + yx
__global__ void k_xsums(const float* __restrict__ x, float* __restrict__ xs1,
                        float* __restrict__ xs2)
{
  int pos = blockIdx.x * 256 + threadIdx.x;   // < 50176
  float s1 = 0.f, s2 = 0.f;
  for (int b = 0; b < BB; b++) {
    float v = x[(size_t)b * 50176 + pos];
    s1 += v; s2 = fmaf(v, v, s2);
  }
  xs1[pos] = s1; xs2[pos] = s2;
}

// fold BN1 into per-(patch,c) scale/shift
__global__ void k_stats1(const float* __restrict__ xs1, const float* __restrict__ xs2,
                         const float* __restrict__ gam, const float* __restrict__ bet,
                         float* __restrict__ ssc, float* __restrict__ ssh)
{
  int p = blockIdx.x;
  int c = blockIdx.y * 256 + threadIdx.x;
  int y1 = p / 5, x1 = p % 5;
  float s1 = 0.f, s2 = 0.f;
  for (int dy = 0; dy < 3; dy++)
    for (int dx = 0; dx < 3; dx++) {
      int pos = c * 49 + (y1 + dy) * 7 + (x1 + dx);
      s1 += xs1[pos]; s2 += xs2[pos];
    }
  const float inv = 1.0f / 2304.0f;
  float mean = s1 * inv;
  float var  = s2 * inv - mean * mean;
  float rs   = rsqrtf(var + EPS);
  float sc   = rs * gam[c];
  ssc[(size_t)p * CC + c] = sc;
  ssh[(size_t)p * CC + c] = bet[c] - mean * sc;
}

// ----------------------------------- patch gather + BN1 affine + relu

__global__ void k_gather(const float* __restrict__ x, const float* __restrict__ ssc,
                         const float* __restrict__ ssh, float* __restrict__ out,
                         int pbase)
{
  int tid = threadIdx.x;
  int r0 = blockIdx.x * 16;
  for (int rr = 0; rr < 16; rr++) {
    int row = r0 + rr;
    int pl = row / 2304;
    int b  = (row / 9) & 255;
    int yx = row % 9;
    int pg = pbase + pl;
    int pos = (pg / 5 + yx / 3) * 7 + (pg % 5) + (yx % 3);
    const float* xb  = x + (size_t)b * CC * 49 + pos;
    const float* scp = ssc + (size_t)pg * CC;
    const float* shp = ssh + (size_t)pg * CC;
    float* op = out + (size_t)row * CC;
    #pragma unroll
    for (int q = 0; q < 4; q++) {
      int c = q * 256 + tid;
      float v = xb[(size_t)c * 49];
      op[c] = fmaxf(fmaf(v, scp[c], shp[c]), 0.f);
    }
  }
}

// ------------------------------------------------------- BN stats (l2,l3)

// partial sums over 72-row groups; grid (PC*32, 4)
__global__ void k_stats_partial(const float* __restrict__ h, float* __restrict__ part,
                                int G)
{
  int pr = blockIdx.x;                 // pl*32 + rg
  int c  = blockIdx.y * 256 + threadIdx.x;
  int pl = pr >> 5, rg = pr & 31;
  const float* hp = h + ((size_t)pl * 2304 + (size_t)rg * 72) * CC + c;
  float s1 = 0.f, s2 = 0.f;
  for (int r = 0; r < 72; r++) {
    float v = hp[(size_t)r * CC];
    s1 += v; s2 = fmaf(v, v, s2);
  }
  part[(size_t)pr * CC + c]       = s1;
  part[(size_t)(G + pr) * CC + c] = s2;
}

__global__ void k_stats_fin(const float* __restrict__ part, const float* __restrict__ gam,
                            const float* __restrict__ bet, float* __restrict__ ssc,
                            float* __restrict__ ssh, int pbase, int G)
{
  int pl = blockIdx.x;
  int c  = blockIdx.y * 256 + threadIdx.x;
  float s1 = 0.f, s2 = 0.f;
  for (int rg = 0; rg < 32; rg++) {
    s1 += part[(size_t)(pl * 32 + rg) * CC + c];
    s2 += part[(size_t)(G + pl * 32 + rg) * CC + c];
  }
  const float inv = 1.0f / 2304.0f;
  float mean = s1 * inv;
  float var  = s2 * inv - mean * mean;
  float rs   = rsqrtf(var + EPS);
  float sc   = rs * gam[c];
  int pg = pbase + pl;
  ssc[(size_t)pg * CC + c] = sc;
  ssh[(size_t)pg * CC + c] = bet[c] - mean * sc;
}

// ------------------------------- BN3 affine + relu + 3x3 mean pooling

__global__ void k_pool(const float* __restrict__ h, const float* __restrict__ ssc,
                       const float* __restrict__ ssh, float* __restrict__ apool,
                       int pbase)
{
  int tid = threadIdx.x;
  int r0 = blockIdx.x * 4;
  for (int rr = 0; rr < 4; rr++) {
    int row = r0 + rr;                 // pl*256 + b
    int pl = row >> 8;
    int pg = pbase + pl;
    #pragma unroll
    for (int q = 0; q < 4; q++) {
      int c = q * 256 + tid;
      float scv = ssc[(size_t)pg * CC + c];
      float shv = ssh[(size_t)pg * CC + c];
      const float* hp = h + (size_t)row * 9 * CC + c;
      float s = 0.f;
      #pragma unroll
      for (int yx = 0; yx < 9; yx++)
        s += fmaxf(fmaf(hp[(size_t)yx * CC], scv, shv), 0.f);
      apool[(size_t)row * CC + c] = s * (1.0f / 9.0f);
    }
  }
}

// ------------------------------------------------------------ GEMM core
// C[m][n] = sum_k f(A[m][k]) * Bw[n][k] + bias[n]
// f = identity, or (AFFINE) relu(a*sc[k]+sh[k]) with per-tile-uniform patch.

#define GM 128
#define GN 128
#define GK 16

template<bool AFFINE>
__device__ __forceinline__ void gemm_body(
    const float* __restrict__ A, const float* __restrict__ Bw,
    const float* __restrict__ bias, float* __restrict__ Cmat,
    int m0, int n0, const float* __restrict__ sc, const float* __restrict__ sh)
{
  __shared__ float As[GK][GM + 4];
  __shared__ float Bs[GK][GN + 4];
  const int tid = threadIdx.x;
  const int tx = tid & 15, ty = tid >> 4;

  float acc[8][8];
  #pragma unroll
  for (int i = 0; i < 8; i++)
    #pragma unroll
    for (int j = 0; j < 8; j++) acc[i][j] = 0.f;

  for (int kk = 0; kk < CC; kk += GK) {
    #pragma unroll
    for (int q = 0; q < 2; q++) {
      int idx = q * 256 + tid;         // 0..511
      int m   = idx >> 2;              // 0..127
      int kq  = (idx & 3) << 2;        // 0,4,8,12
      float4 av = *(const float4*)(A + (size_t)(m0 + m) * CC + kk + kq);
      if (AFFINE) {
        float4 scv = *(const float4*)(sc + kk + kq);
        float4 shv = *(const float4*)(sh + kk + kq);
        av.x = fmaxf(fmaf(av.x, scv.x, shv.x), 0.f);
        av.y = fmaxf(fmaf(av.y, scv.y, shv.y), 0.f);
        av.z = fmaxf(fmaf(av.z, scv.z, shv.z), 0.f);
        av.w = fmaxf(fmaf(av.w, scv.w, shv.w), 0.f);
      }
      As[kq + 0][m] = av.x; As[kq + 1][m] = av.y;
      As[kq + 2][m] = av.z; As[kq + 3][m] = av.w;
      float4 bv = *(const float4*)(Bw + (size_t)(n0 + m) * CC + kk + kq);
      Bs[kq + 0][m] = bv.x; Bs[kq + 1][m] = bv.y;
      Bs[kq + 2][m] = bv.z; Bs[kq + 3][m] = bv.w;
    }
    __syncthreads();
    #pragma unroll
    for (int k = 0; k < GK; k++) {
      float a[8], b[8];
      *(float4*)&a[0] = *(const float4*)&As[k][ty * 4];
      *(float4*)&a[4] = *(const float4*)&As[k][ty * 4 + 64];
      *(float4*)&b[0] = *(const float4*)&Bs[k][tx * 4];
      *(float4*)&b[4] = *(const float4*)&Bs[k][tx * 4 + 64];
      #pragma unroll
      for (int i = 0; i < 8; i++)
        #pragma unroll
        for (int j = 0; j < 8; j++)
          acc[i][j] = fmaf(a[i], b[j], acc[i][j]);
    }
    __syncthreads();
  }

  float bc[8];
  *(float4*)&bc[0] = *(const float4*)(bias + n0 + tx * 4);
  *(float4*)&bc[4] = *(const float4*)(bias + n0 + tx * 4 + 64);
  #pragma unroll
  for (int i = 0; i < 8; i++) {
    int row = m0 + ty * 4 + (i & 3) + (i >> 2) * 64;
    float4 v0 = { acc[i][0] + bc[0], acc[i][1] + bc[1], acc[i][2] + bc[2], acc[i][3] + bc[3] };
    float4 v1 = { acc[i][4] + bc[4], acc[i][5] + bc[5], acc[i][6] + bc[6], acc[i][7] + bc[7] };
    *(float4*)(Cmat + (size_t)row * CC + n0 + tx * 4)      = v0;
    *(float4*)(Cmat + (size_t)row * CC + n0 + tx * 4 + 64) = v1;
  }
}

template<bool AFFINE>
__global__ __launch_bounds__(256)
void k_gemm(const float* __restrict__ A, const float* __restrict__ Bw,
            const float* __restrict__ bias, float* __restrict__ Cmat,
            const float* __restrict__ ssc, const float* __restrict__ ssh, int pbase)
{
  int m0 = blockIdx.x * GM;
  int n0 = blockIdx.y * GN;
  const float *sc = nullptr, *sh = nullptr;
  if (AFFINE) {
    int p = pbase + m0 / 2304;         // 2304 = 18*GM -> tile never crosses patch
    sc = ssc + (size_t)p * CC;
    sh = ssh + (size_t)p * CC;
  }
  gemm_body<AFFINE>(A, Bw, bias, Cmat, m0, n0, sc, sh);
}

__global__ __launch_bounds__(256)
void k_heads(const float* __restrict__ ctx, const float* __restrict__ lw,
             const float* __restrict__ lb, float* __restrict__ out)
{
  int t = blockIdx.x;                  // 0..15 : (m-tile<<3)|n-tile
  int j = blockIdx.y;                  // 0..119
  int p, w;
  head_entry(j, &p, &w);
  gemm_body<false>(ctx + (size_t)p * BB * CC,
                   lw + (size_t)w * CC * CC,
                   lb + (size_t)w * CC,
                   out + (size_t)j * BB * CC,
                   (t >> 3) * GM, (t & 7) * GN, nullptr, nullptr);
}

// ---------------------------------------------------------------- launch

extern "C" void kernel_launch(void* const* d_in, const int* in_sizes, int n_in,
                              void* d_out, int out_size, void* d_ws, size_t ws_size,
                              hipStream_t stream)
{
  const float* x   = (const float*)d_in[0];
  const float* bng = (const float*)d_in[1];
  const float* bnb = (const float*)d_in[2];
  const float* cw  = (const float*)d_in[3];
  const float* cb  = (const float*)d_in[4];
  const float* lw  = (const float*)d_in[5];
  const float* lb  = (const float*)d_in[6];
  float* out = (float*)d_out;
  float* ws  = (float*)d_ws;

  // pick chunk size (patches per pass) that fits the workspace
  auto need_f = [](int PC) -> size_t {
    size_t Mc = (size_t)PC * 2304;
    return 2 * Mc * CC            // ha, hb
         + (size_t)NP * BB * CC   // ctx
         + 2 * 50176              // xsums
         + 2 * (size_t)NP * CC    // scale/shift
         + 2 * (size_t)PC * 32 * CC; // stats partials
  };
  int PC = 5;
  if (ws_size < need_f(5) * sizeof(float)) PC = 1;
  const int NCH = NP / PC;
  const size_t Mc = (size_t)PC * 2304;
  const int G = PC * 32;

  float* ha   = ws;
  float* hb   = ha + Mc * CC;
  float* ctx  = hb + Mc * CC;
  float* xs1  = ctx + (size_t)NP * BB * CC;
  float* xs2  = xs1 + 50176;
  float* ssc  = xs2 + 50176;
  float* ssh  = ssc + (size_t)NP * CC;
  float* part = ssh + (size_t)NP * CC;

  // layer-1 stats for all 25 patches (from x directly)
  k_xsums<<<196, 256, 0, stream>>>(x, xs1, xs2);
  k_stats1<<<dim3(25, 4), 256, 0, stream>>>(xs1, xs2, bng, bnb, ssc, ssh);

  for (int chunk = 0; chunk < NCH; ++chunk) {
    const int pbase = chunk * PC;
    // patches + BN1 + relu -> ha
    k_gather<<<(int)(Mc / 16), 256, 0, stream>>>(x, ssc, ssh, ha, pbase);
    // conv1: ha -> hb
    k_gemm<false><<<dim3((int)(Mc / GM), CC / GN), 256, 0, stream>>>(
        ha, cw, cb, hb, nullptr, nullptr, 0);
    // BN2 stats on hb
    k_stats_partial<<<dim3(G, 4), 256, 0, stream>>>(hb, part, G);
    k_stats_fin<<<dim3(PC, 4), 256, 0, stream>>>(part, bng + CC, bnb + CC, ssc, ssh, pbase, G);
    // BN2+relu (fused) + conv2: hb -> ha
    k_gemm<true><<<dim3((int)(Mc / GM), CC / GN), 256, 0, stream>>>(
        hb, cw + (size_t)CC * CC, cb + CC, ha, ssc, ssh, pbase);
    // BN3 stats on ha
    k_stats_partial<<<dim3(G, 4), 256, 0, stream>>>(ha, part, G);
    k_stats_fin<<<dim3(PC, 4), 256, 0, stream>>>(part, bng + 2 * CC, bnb + 2 * CC, ssc, ssh, pbase, G);
    // BN3+relu+pool: ha -> apool (stored at hb, which is dead now)
    k_pool<<<PC * 64, 256, 0, stream>>>(ha, ssc, ssh, hb, pbase);
    // conv3 on pooled rows: -> ctx slice
    k_gemm<false><<<dim3(PC * BB / GM, CC / GN), 256, 0, stream>>>(
        hb, cw + 2 * (size_t)CC * CC, cb + 2 * CC,
        ctx + (size_t)pbase * BB * CC, nullptr, nullptr, 0);
  }

  // 120 prediction heads
  k_heads<<<dim3(16, 120), 256, 0, stream>>>(ctx, lw, lb, out);
}

// Round 2
// 1909.008 us; speedup vs baseline: 2.4657x; 2.4657x over previous
//
#include <hip/hip_runtime.h>
#include <hip/hip_bf16.h>

#define BB 256
#define CC 1024
#define NP 25
#define EPS 1e-5f

typedef __attribute__((ext_vector_type(8))) short bf16x8;
typedef __attribute__((ext_vector_type(4))) float f32x4;
typedef unsigned int u32;

#define MFMA16(A, B, C) __builtin_amdgcn_mfma_f32_16x16x32_bf16(A, B, C, 0, 0, 0)

// ---------------------------------------------------------------- utils

__device__ __forceinline__ void head_entry(int j, int* pp, int* ww)
{
  int cnt = 0;
  for (int y1 = 0; y1 < 5; y1++)
    for (int x1 = 0; x1 < 5; x1++) {
      int p = y1 * 5 + x1;
      int y2 = y1 + 2, x2 = x1 + 2;
      if (y2 == 2 || y2 == 3)
        for (int s = 0; s < 3; s++) { if (y2 + s + 1 > 6) break; if (cnt == j) { *pp = p; *ww = 0 + s; return; } cnt++; }
      if (y1 == 3 || y1 == 4)
        for (int s = 0; s < 3; s++) { if (y1 - (s + 1) < 0) break; if (cnt == j) { *pp = p; *ww = 3 + s; return; } cnt++; }
      if (x2 == 2 || x2 == 3)
        for (int s = 0; s < 3; s++) { if (x2 + s + 1 > 6) break; if (cnt == j) { *pp = p; *ww = 6 + s; return; } cnt++; }
      if (x1 == 3 || x1 == 4)
        for (int s = 0; s < 3; s++) { if (x1 - (s + 1) < 0) break; if (cnt == j) { *pp = p; *ww = 9 + s; return; } cnt++; }
    }
}

// split one float into bf16 hi (truncate) + bf16 lo (remainder, truncate);
// pack two consecutive elements into one u32 (elem k low half, k+1 high).
__device__ __forceinline__ void split_f4(float4 f, uint2& h, uint2& l)
{
  u32 ux = __float_as_uint(f.x), uy = __float_as_uint(f.y);
  u32 uz = __float_as_uint(f.z), uw = __float_as_uint(f.w);
  h.x = (ux >> 16) | (uy & 0xFFFF0000u);
  h.y = (uz >> 16) | (uw & 0xFFFF0000u);
  float lx = f.x - __uint_as_float(ux & 0xFFFF0000u);
  float ly = f.y - __uint_as_float(uy & 0xFFFF0000u);
  float lz = f.z - __uint_as_float(uz & 0xFFFF0000u);
  float lw = f.w - __uint_as_float(uw & 0xFFFF0000u);
  l.x = (__float_as_uint(lx) >> 16) | (__float_as_uint(ly) & 0xFFFF0000u);
  l.y = (__float_as_uint(lz) >> 16) | (__float_as_uint(lw) & 0xFFFF0000u);
}

// ------------------------------------------------- layer-1 stats from x

__global__ void k_xsums(const float* __restrict__ x, float* __restrict__ xs1,
                        float* __restrict__ xs2)
{
  int pos = blockIdx.x * 256 + threadIdx.x;   // < 50176
  float s1 = 0.f, s2 = 0.f;
  for (int b = 0; b < BB; b++) {
    float v = x[(size_t)b * 50176 + pos];
    s1 += v; s2 = fmaf(v, v, s2);
  }
  xs1[pos] = s1; xs2[pos] = s2;
}

__global__ void k_stats1(const float* __restrict__ xs1, const float* __restrict__ xs2,
                         const float* __restrict__ gam, const float* __restrict__ bet,
                         float* __restrict__ ssc, float* __restrict__ ssh)
{
  int p = blockIdx.x;
  int c = blockIdx.y * 256 + threadIdx.x;
  int y1 = p / 5, x1 = p % 5;
  float s1 = 0.f, s2 = 0.f;
  for (int dy = 0; dy < 3; dy++)
    for (int dx = 0; dx < 3; dx++) {
      int pos = c * 49 + (y1 + dy) * 7 + (x1 + dx);
      s1 += xs1[pos]; s2 += xs2[pos];
    }
  const float inv = 1.0f / 2304.0f;
  float mean = s1 * inv;
  float var  = s2 * inv - mean * mean;
  float rs   = rsqrtf(var + EPS);
  float sc   = rs * gam[c];
  ssc[(size_t)p * CC + c] = sc;
  ssh[(size_t)p * CC + c] = bet[c] - mean * sc;
}

// ----------------------------------- patch gather + BN1 affine + relu

__global__ void k_gather(const float* __restrict__ x, const float* __restrict__ ssc,
                         const float* __restrict__ ssh, float* __restrict__ out,
                         int pbase)
{
  int tid = threadIdx.x;
  int r0 = blockIdx.x * 16;
  for (int rr = 0; rr < 16; rr++) {
    int row = r0 + rr;
    int pl = row / 2304;
    int b  = (row / 9) & 255;
    int yx = row % 9;
    int pg = pbase + pl;
    int pos = (pg / 5 + yx / 3) * 7 + (pg % 5) + (yx % 3);
    const float* xb  = x + (size_t)b * CC * 49 + pos;
    const float* scp = ssc + (size_t)pg * CC;
    const float* shp = ssh + (size_t)pg * CC;
    float* op = out + (size_t)row * CC;
    #pragma unroll
    for (int q = 0; q < 4; q++) {
      int c = q * 256 + tid;
      float v = xb[(size_t)c * 49];
      op[c] = fmaxf(fmaf(v, scp[c], shp[c]), 0.f);
    }
  }
}

// ------------------------------------------------------- BN stats (l2,l3)

__global__ void k_stats_partial(const float* __restrict__ h, float* __restrict__ part,
                                int G)
{
  int pr = blockIdx.x;                 // pl*32 + rg
  int c  = blockIdx.y * 256 + threadIdx.x;
  int pl = pr >> 5, rg = pr & 31;
  const float* hp = h + ((size_t)pl * 2304 + (size_t)rg * 72) * CC + c;
  float s1 = 0.f, s2 = 0.f;
  for (int r = 0; r < 72; r++) {
    float v = hp[(size_t)r * CC];
    s1 += v; s2 = fmaf(v, v, s2);
  }
  part[(size_t)pr * CC + c]       = s1;
  part[(size_t)(G + pr) * CC + c] = s2;
}

__global__ void k_stats_fin(const float* __restrict__ part, const float* __restrict__ gam,
                            const float* __restrict__ bet, float* __restrict__ ssc,
                            float* __restrict__ ssh, int pbase, int G)
{
  int pl = blockIdx.x;
  int c  = blockIdx.y * 256 + threadIdx.x;
  float s1 = 0.f, s2 = 0.f;
  for (int rg = 0; rg < 32; rg++) {
    s1 += part[(size_t)(pl * 32 + rg) * CC + c];
    s2 += part[(size_t)(G + pl * 32 + rg) * CC + c];
  }
  const float inv = 1.0f / 2304.0f;
  float mean = s1 * inv;
  float var  = s2 * inv - mean * mean;
  float rs   = rsqrtf(var + EPS);
  float sc   = rs * gam[c];
  int pg = pbase + pl;
  ssc[(size_t)pg * CC + c] = sc;
  ssh[(size_t)pg * CC + c] = bet[c] - mean * sc;
}

// ------------------------------- BN3 affine + relu + 3x3 mean pooling

__global__ void k_pool(const float* __restrict__ h, const float* __restrict__ ssc,
                       const float* __restrict__ ssh, float* __restrict__ apool,
                       int pbase)
{
  int tid = threadIdx.x;
  int r0 = blockIdx.x * 4;
  for (int rr = 0; rr < 4; rr++) {
    int row = r0 + rr;                 // pl*256 + b
    int pl = row >> 8;
    int pg = pbase + pl;
    #pragma unroll
    for (int q = 0; q < 4; q++) {
      int c = q * 256 + tid;
      float scv = ssc[(size_t)pg * CC + c];
      float shv = ssh[(size_t)pg * CC + c];
      const float* hp = h + (size_t)row * 9 * CC + c;
      float s = 0.f;
      #pragma unroll
      for (int yx = 0; yx < 9; yx++)
        s += fmaxf(fmaf(hp[(size_t)yx * CC], scv, shv), 0.f);
      apool[(size_t)row * CC + c] = s * (1.0f / 9.0f);
    }
  }
}

// --------------------------------------- weight pre-split (fp32 -> hi/lo bf16)
// per matrix (1024x1024): 512K u32 hi plane then 512K u32 lo plane.

__global__ void k_wsplit(const float* __restrict__ w, u32* __restrict__ dstbase, int npair)
{
  int g = blockIdx.x * 256 + threadIdx.x;
  if (g >= npair) return;
  int mat = g >> 19, pr = g & 524287;
  const float* src = w + ((size_t)mat << 20) + 2 * (size_t)pr;
  float fx = src[0], fy = src[1];
  u32 ux = __float_as_uint(fx), uy = __float_as_uint(fy);
  u32 hi = (ux >> 16) | (uy & 0xFFFF0000u);
  float lx = fx - __uint_as_float(ux & 0xFFFF0000u);
  float ly = fy - __uint_as_float(uy & 0xFFFF0000u);
  u32 lo = (__float_as_uint(lx) >> 16) | (__float_as_uint(ly) & 0xFFFF0000u);
  u32* dst = dstbase + ((size_t)mat << 20);
  dst[pr] = hi;
  dst[524288 + pr] = lo;
}

// ------------------------------------------------------------ MFMA GEMM core
// C[m][n] = sum_k f(A[m][k]) * B[n][k] + bias[n]   (both operands K-contiguous)
// split-bf16: each fp32 -> hi+lo bf16; acc += ah*bh + al*bh + ah*bl (fp32 MFMA acc)
// AMODE: 0 = fp32+convert, 1 = fp32+affine(relu)+convert
// BPRE : true = B pre-split planes, false = fp32+convert

#define TM 128
#define TN 128
#define TK 32
#define LROW 20   // u32 per LDS row (80 B) -> conflict-optimal ds_read_b128

template<int AMODE, bool BPRE>
__device__ __forceinline__ void mgemm_body(
    const float* __restrict__ A, const float* __restrict__ Bf,
    const u32* __restrict__ Bp, const float* __restrict__ bias,
    float* __restrict__ Cmat, int m0, int n0,
    const float* __restrict__ sc, const float* __restrict__ sh)
{
  __shared__ u32 lds[4 * 128 * LROW];
  u32* Ah = lds;
  u32* Al = lds + 128 * LROW;
  u32* Bh = lds + 2 * 128 * LROW;
  u32* Bl = lds + 3 * 128 * LROW;

  const int t    = threadIdx.x;
  const int r    = t >> 1;        // staging row 0..127
  const int half = t & 1;         // 16-float half of the 32-wide K slab
  const int l    = t & 63;
  const int wv   = t >> 6;
  const int wm   = (wv >> 1) * 64, wn = (wv & 1) * 64;
  const int lr   = l & 15;        // frag row/col
  const int lk   = l >> 4;        // frag k-group

  f32x4 acc[4][4];
  #pragma unroll
  for (int i = 0; i < 4; i++)
    #pragma unroll
    for (int j = 0; j < 4; j++) { f32x4 z = {0.f, 0.f, 0.f, 0.f}; acc[i][j] = z; }

  const float* arow = A + (size_t)(m0 + r) * CC + half * 16;
  const u32 wbase = r * LROW + half * 8;

  for (int kk = 0; kk < CC; kk += TK) {
    // ---- global loads (issued before the barrier: overlap w/ prev compute)
    float4 a0 = *(const float4*)(arow + kk);
    float4 a1 = *(const float4*)(arow + kk + 4);
    float4 a2 = *(const float4*)(arow + kk + 8);
    float4 a3 = *(const float4*)(arow + kk + 12);
    uint4 bh0, bh1, bl0, bl1;
    if (BPRE) {
      const u32* bhp = Bp + (size_t)(n0 + r) * 512 + (kk >> 1) + half * 8;
      bh0 = *(const uint4*)(bhp);
      bh1 = *(const uint4*)(bhp + 4);
      bl0 = *(const uint4*)(bhp + 524288);
      bl1 = *(const uint4*)(bhp + 524288 + 4);
    } else {
      const float* brow = Bf + (size_t)(n0 + r) * CC + half * 16 + kk;
      float4 b0 = *(const float4*)(brow);
      float4 b1 = *(const float4*)(brow + 4);
      float4 b2 = *(const float4*)(brow + 8);
      float4 b3 = *(const float4*)(brow + 12);
      uint2 h0, l0, h1, l1, h2, l2, h3, l3;
      split_f4(b0, h0, l0); split_f4(b1, h1, l1);
      split_f4(b2, h2, l2); split_f4(b3, h3, l3);
      bh0 = make_uint4(h0.x, h0.y, h1.x, h1.y);
      bh1 = make_uint4(h2.x, h2.y, h3.x, h3.y);
      bl0 = make_uint4(l0.x, l0.y, l1.x, l1.y);
      bl1 = make_uint4(l2.x, l2.y, l3.x, l3.y);
    }
    if (AMODE == 1) {
      const float* scp = sc + half * 16 + kk;
      const float* shp = sh + half * 16 + kk;
      float4 s0 = *(const float4*)(scp),     s1 = *(const float4*)(scp + 4);
      float4 s2 = *(const float4*)(scp + 8), s3 = *(const float4*)(scp + 12);
      float4 t0 = *(const float4*)(shp),     t1 = *(const float4*)(shp + 4);
      float4 t2 = *(const float4*)(shp + 8), t3 = *(const float4*)(shp + 12);
      a0.x = fmaxf(fmaf(a0.x, s0.x, t0.x), 0.f); a0.y = fmaxf(fmaf(a0.y, s0.y, t0.y), 0.f);
      a0.z = fmaxf(fmaf(a0.z, s0.z, t0.z), 0.f); a0.w = fmaxf(fmaf(a0.w, s0.w, t0.w), 0.f);
      a1.x = fmaxf(fmaf(a1.x, s1.x, t1.x), 0.f); a1.y = fmaxf(fmaf(a1.y, s1.y, t1.y), 0.f);
      a1.z = fmaxf(fmaf(a1.z, s1.z, t1.z), 0.f); a1.w = fmaxf(fmaf(a1.w, s1.w, t1.w), 0.f);
      a2.x = fmaxf(fmaf(a2.x, s2.x, t2.x), 0.f); a2.y = fmaxf(fmaf(a2.y, s2.y, t2.y), 0.f);
      a2.z = fmaxf(fmaf(a2.z, s2.z, t2.z), 0.f); a2.w = fmaxf(fmaf(a2.w, s2.w, t2.w), 0.f);
      a3.x = fmaxf(fmaf(a3.x, s3.x, t3.x), 0.f); a3.y = fmaxf(fmaf(a3.y, s3.y, t3.y), 0.f);
      a3.z = fmaxf(fmaf(a3.z, s3.z, t3.z), 0.f); a3.w = fmaxf(fmaf(a3.w, s3.w, t3.w), 0.f);
    }
    uint2 ah0, al0, ah1, al1, ah2, al2, ah3, al3;
    split_f4(a0, ah0, al0); split_f4(a1, ah1, al1);
    split_f4(a2, ah2, al2); split_f4(a3, ah3, al3);

    __syncthreads();   // prev iteration's frag reads done
    *(uint4*)&Ah[wbase]     = make_uint4(ah0.x, ah0.y, ah1.x, ah1.y);
    *(uint4*)&Ah[wbase + 4] = make_uint4(ah2.x, ah2.y, ah3.x, ah3.y);
    *(uint4*)&Al[wbase]     = make_uint4(al0.x, al0.y, al1.x, al1.y);
    *(uint4*)&Al[wbase + 4] = make_uint4(al2.x, al2.y, al3.x, al3.y);
    *(uint4*)&Bh[wbase]     = bh0;
    *(uint4*)&Bh[wbase + 4] = bh1;
    *(uint4*)&Bl[wbase]     = bl0;
    *(uint4*)&Bl[wbase + 4] = bl1;
    __syncthreads();

    bf16x8 afh[4], afl[4], bfh[4], bfl[4];
    #pragma unroll
    for (int i = 0; i < 4; i++) {
      int ar = (wm + i * 16 + lr) * LROW + lk * 4;
      int br = (wn + i * 16 + lr) * LROW + lk * 4;
      afh[i] = *(const bf16x8*)&Ah[ar];
      afl[i] = *(const bf16x8*)&Al[ar];
      bfh[i] = *(const bf16x8*)&Bh[br];
      bfl[i] = *(const bf16x8*)&Bl[br];
    }
    #pragma unroll
    for (int i = 0; i < 4; i++)
      #pragma unroll
      for (int j = 0; j < 4; j++) {
        acc[i][j] = MFMA16(afh[i], bfh[j], acc[i][j]);
        acc[i][j] = MFMA16(afl[i], bfh[j], acc[i][j]);
        acc[i][j] = MFMA16(afh[i], bfl[j], acc[i][j]);
      }
  }

  // epilogue: D row = lk*4 + reg, col = lr  [m89 layout]
  #pragma unroll
  for (int j = 0; j < 4; j++) {
    int ocol = n0 + wn + j * 16 + lr;
    float bj = bias[ocol];
    #pragma unroll
    for (int i = 0; i < 4; i++) {
      int orow = m0 + wm + i * 16 + lk * 4;
      float* cp = Cmat + (size_t)orow * CC + ocol;
      #pragma unroll
      for (int reg = 0; reg < 4; reg++)
        cp[(size_t)reg * CC] = acc[i][j][reg] + bj;
    }
  }
}

template<int AMODE, bool BPRE>
__global__ __launch_bounds__(256, 2)
void k_mgemm(const float* __restrict__ A, const float* __restrict__ Bf,
             const u32* __restrict__ Bp, const float* __restrict__ bias,
             float* __restrict__ Cmat, const float* __restrict__ ssc,
             const float* __restrict__ ssh, int pbase)
{
  int m0 = blockIdx.x * TM;
  int n0 = blockIdx.y * TN;
  const float *sc = nullptr, *sh = nullptr;
  if (AMODE == 1) {
    int p = pbase + m0 / 2304;         // tile never crosses patch boundary
    sc = ssc + (size_t)p * CC;
    sh = ssh + (size_t)p * CC;
  }
  mgemm_body<AMODE, BPRE>(A, Bf, Bp, bias, Cmat, m0, n0, sc, sh);
}

template<bool BPRE>
__global__ __launch_bounds__(256, 2)
void k_mheads(const float* __restrict__ ctx, const float* __restrict__ lw,
              const u32* __restrict__ lwp, const float* __restrict__ lb,
              float* __restrict__ out)
{
  int tt = blockIdx.x;                 // (m-tile<<3)|n-tile
  int j = blockIdx.y;                  // 0..119
  int p, wsel;
  head_entry(j, &p, &wsel);
  mgemm_body<0, BPRE>(ctx + (size_t)p * BB * CC,
                      lw + (size_t)wsel * CC * CC,
                      BPRE ? lwp + ((size_t)wsel << 20) : nullptr,
                      lb + (size_t)wsel * CC,
                      out + (size_t)j * BB * CC,
                      (tt >> 3) * TM, (tt & 7) * TN, nullptr, nullptr);
}

// ---------------------------------------------------------------- launch

extern "C" void kernel_launch(void* const* d_in, const int* in_sizes, int n_in,
                              void* d_out, int out_size, void* d_ws, size_t ws_size,
                              hipStream_t stream)
{
  const float* x   = (const float*)d_in[0];
  const float* bng = (const float*)d_in[1];
  const float* bnb = (const float*)d_in[2];
  const float* cw  = (const float*)d_in[3];
  const float* cb  = (const float*)d_in[4];
  const float* lw  = (const float*)d_in[5];
  const float* lb  = (const float*)d_in[6];
  float* out = (float*)d_out;
  float* ws  = (float*)d_ws;

  auto need_f = [](int PC) -> size_t {
    size_t Mc = (size_t)PC * 2304;
    return 2 * Mc * CC + (size_t)NP * BB * CC + 2 * 50176
         + 2 * (size_t)NP * CC + 2 * (size_t)PC * 32 * CC;
  };
  int PC = 5;
  if (ws_size < need_f(5) * sizeof(float)) PC = 1;
  const int NCH = NP / PC;
  const size_t Mc = (size_t)PC * 2304;
  const int G = PC * 32;

  float* ha   = ws;
  float* hb   = ha + Mc * CC;
  float* ctx  = hb + Mc * CC;
  float* xs1  = ctx + (size_t)NP * BB * CC;
  float* xs2  = xs1 + 50176;
  float* ssc  = xs2 + 50176;
  float* ssh  = ssc + (size_t)NP * CC;
  float* part = ssh + (size_t)NP * CC;
  u32*   wpl  = (u32*)(part + 2 * (size_t)G * CC);

  // weight pre-split planes: 15 matrices x 1M u32 (hi 512K, lo 512K)
  const bool pre =
      ((char*)(wpl + 15ull * 1048576) - (char*)ws) <= (ptrdiff_t)ws_size;

  if (pre) {
    k_wsplit<<<(3 * 524288) / 256, 256, 0, stream>>>(cw, wpl, 3 * 524288);
    k_wsplit<<<(12 * 524288) / 256, 256, 0, stream>>>(lw, wpl + 3ull * 1048576,
                                                      12 * 524288);
  }

  k_xsums<<<196, 256, 0, stream>>>(x, xs1, xs2);
  k_stats1<<<dim3(25, 4), 256, 0, stream>>>(xs1, xs2, bng, bnb, ssc, ssh);

  const dim3 gconv((int)(Mc / TM), CC / TN);
  const dim3 gpool(PC * BB / TM, CC / TN);

  for (int chunk = 0; chunk < NCH; ++chunk) {
    const int pbase = chunk * PC;
    k_gather<<<(int)(Mc / 16), 256, 0, stream>>>(x, ssc, ssh, ha, pbase);
    // conv1: ha -> hb
    if (pre)
      k_mgemm<0, true><<<gconv, 256, 0, stream>>>(ha, cw, wpl, cb, hb, nullptr, nullptr, 0);
    else
      k_mgemm<0, false><<<gconv, 256, 0, stream>>>(ha, cw, nullptr, cb, hb, nullptr, nullptr, 0);
    // BN2 stats
    k_stats_partial<<<dim3(G, 4), 256, 0, stream>>>(hb, part, G);
    k_stats_fin<<<dim3(PC, 4), 256, 0, stream>>>(part, bng + CC, bnb + CC, ssc, ssh, pbase, G);
    // BN2+relu fused + conv2: hb -> ha
    if (pre)
      k_mgemm<1, true><<<gconv, 256, 0, stream>>>(hb, cw + (size_t)CC * CC,
          wpl + 1ull * 1048576, cb + CC, ha, ssc, ssh, pbase);
    else
      k_mgemm<1, false><<<gconv, 256, 0, stream>>>(hb, cw + (size_t)CC * CC,
          nullptr, cb + CC, ha, ssc, ssh, pbase);
    // BN3 stats
    k_stats_partial<<<dim3(G, 4), 256, 0, stream>>>(ha, part, G);
    k_stats_fin<<<dim3(PC, 4), 256, 0, stream>>>(part, bng + 2 * CC, bnb + 2 * CC, ssc, ssh, pbase, G);
    // BN3+relu+pool: ha -> hb (dead region reused)
    k_pool<<<PC * 64, 256, 0, stream>>>(ha, ssc, ssh, hb, pbase);
    // conv3 on pooled rows -> ctx slice
    if (pre)
      k_mgemm<0, true><<<gpool, 256, 0, stream>>>(hb, cw + 2 * (size_t)CC * CC,
          wpl + 2ull * 1048576, cb + 2 * CC, ctx + (size_t)pbase * BB * CC,
          nullptr, nullptr, 0);
    else
      k_mgemm<0, false><<<gpool, 256, 0, stream>>>(hb, cw + 2 * (size_t)CC * CC,
          nullptr, cb + 2 * CC, ctx + (size_t)pbase * BB * CC,
          nullptr, nullptr, 0);
  }

  // 120 prediction heads
  if (pre)
    k_mheads<true><<<dim3(16, 120), 256, 0, stream>>>(ctx, lw, wpl + 3ull * 1048576, lb, out);
  else
    k_mheads<false><<<dim3(16, 120), 256, 0, stream>>>(ctx, lw, nullptr, lb, out);
}

// Round 5
// 1828.044 us; speedup vs baseline: 2.5749x; 1.0443x over previous
//
#include <hip/hip_runtime.h>
#include <hip/hip_bf16.h>
#include <stdint.h>

#define BB 256
#define CC 1024
#define NP 25
#define EPS 1e-5f

typedef __attribute__((ext_vector_type(8))) short bf16x8;
typedef __attribute__((ext_vector_type(4))) float f32x4;
typedef unsigned int u32;

#define MFMA16(A, B, C) __builtin_amdgcn_mfma_f32_16x16x32_bf16(A, B, C, 0, 0, 0)

// async global->LDS, 16B per lane; LDS dest = wave-uniform base + lane*16
__device__ __forceinline__ void gload16(const u32* g, u32* l)
{
  __builtin_amdgcn_global_load_lds(
      (const __attribute__((address_space(1))) u32*)g,
      (__attribute__((address_space(3))) u32*)l, 16, 0, 0);
}

// ---------------------------------------------------------------- utils

__device__ __forceinline__ void head_entry(int j, int* pp, int* ww)
{
  int cnt = 0;
  for (int y1 = 0; y1 < 5; y1++)
    for (int x1 = 0; x1 < 5; x1++) {
      int p = y1 * 5 + x1;
      int y2 = y1 + 2, x2 = x1 + 2;
      if (y2 == 2 || y2 == 3)
        for (int s = 0; s < 3; s++) { if (y2 + s + 1 > 6) break; if (cnt == j) { *pp = p; *ww = 0 + s; return; } cnt++; }
      if (y1 == 3 || y1 == 4)
        for (int s = 0; s < 3; s++) { if (y1 - (s + 1) < 0) break; if (cnt == j) { *pp = p; *ww = 3 + s; return; } cnt++; }
      if (x2 == 2 || x2 == 3)
        for (int s = 0; s < 3; s++) { if (x2 + s + 1 > 6) break; if (cnt == j) { *pp = p; *ww = 6 + s; return; } cnt++; }
      if (x1 == 3 || x1 == 4)
        for (int s = 0; s < 3; s++) { if (x1 - (s + 1) < 0) break; if (cnt == j) { *pp = p; *ww = 9 + s; return; } cnt++; }
    }
}

// split fp32 -> hi bf16 (truncate) + lo bf16 (remainder); pack pairs into u32
__device__ __forceinline__ void split_f4(float4 f, uint2& h, uint2& l)
{
  u32 ux = __float_as_uint(f.x), uy = __float_as_uint(f.y);
  u32 uz = __float_as_uint(f.z), uw = __float_as_uint(f.w);
  h.x = (ux >> 16) | (uy & 0xFFFF0000u);
  h.y = (uz >> 16) | (uw & 0xFFFF0000u);
  float lx = f.x - __uint_as_float(ux & 0xFFFF0000u);
  float ly = f.y - __uint_as_float(uy & 0xFFFF0000u);
  float lz = f.z - __uint_as_float(uz & 0xFFFF0000u);
  float lw = f.w - __uint_as_float(uw & 0xFFFF0000u);
  l.x = (__float_as_uint(lx) >> 16) | (__float_as_uint(ly) & 0xFFFF0000u);
  l.y = (__float_as_uint(lz) >> 16) | (__float_as_uint(lw) & 0xFFFF0000u);
}

// ------------------------------------------------- layer-1 stats from x

__global__ void k_xsums(const float* __restrict__ x, float* __restrict__ xs1,
                        float* __restrict__ xs2)
{
  int pos = blockIdx.x * 256 + threadIdx.x;   // < 50176
  float s1 = 0.f, s2 = 0.f;
  for (int b = 0; b < BB; b++) {
    float v = x[(size_t)b * 50176 + pos];
    s1 += v; s2 = fmaf(v, v, s2);
  }
  xs1[pos] = s1; xs2[pos] = s2;
}

__global__ void k_stats1(const float* __restrict__ xs1, const float* __restrict__ xs2,
                         const float* __restrict__ gam, const float* __restrict__ bet,
                         float* __restrict__ ssc, float* __restrict__ ssh)
{
  int p = blockIdx.x;
  int c = blockIdx.y * 256 + threadIdx.x;
  int y1 = p / 5, x1 = p % 5;
  float s1 = 0.f, s2 = 0.f;
  for (int dy = 0; dy < 3; dy++)
    for (int dx = 0; dx < 3; dx++) {
      int pos = c * 49 + (y1 + dy) * 7 + (x1 + dx);
      s1 += xs1[pos]; s2 += xs2[pos];
    }
  const float inv = 1.0f / 2304.0f;
  float mean = s1 * inv;
  float var  = s2 * inv - mean * mean;
  float rs   = rsqrtf(var + EPS);
  float sc   = rs * gam[c];
  ssc[(size_t)p * CC + c] = sc;
  ssh[(size_t)p * CC + c] = bet[c] - mean * sc;
}

// ------------------------- one-time x transpose: x[b][c][yx] -> xt[b][yx][c]

__global__ void k_transpose(const float* __restrict__ x, float* __restrict__ xt)
{
  __shared__ float tile[128][51];
  int b = blockIdx.x, cg = blockIdx.y;
  const float* src = x + (size_t)b * 50176 + (size_t)cg * 128 * 49;
  for (int idx = threadIdx.x; idx < 6272; idx += 256)
    tile[idx / 49][idx % 49] = src[idx];
  __syncthreads();
  float* dst = xt + (size_t)b * 49 * 1024 + cg * 128;
  for (int pp = 0; pp < 50; pp += 2) {
    int p = pp + (threadIdx.x >> 7);
    int i = threadIdx.x & 127;
    if (p < 49) dst[(size_t)p * 1024 + i] = tile[i][p];
  }
}

// -------------- fallback patch gather + BN1 affine + relu (small-ws tier)

__global__ void k_gather(const float* __restrict__ x, const float* __restrict__ ssc,
                         const float* __restrict__ ssh, float* __restrict__ out,
                         int pbase)
{
  int tid = threadIdx.x;
  int r0 = blockIdx.x * 16;
  for (int rr = 0; rr < 16; rr++) {
    int row = r0 + rr;
    int pl = row / 2304;
    int b  = (row / 9) & 255;
    int yx = row % 9;
    int pg = pbase + pl;
    int pos = (pg / 5 + yx / 3) * 7 + (pg % 5) + (yx % 3);
    const float* xb  = x + (size_t)b * CC * 49 + pos;
    const float* scp = ssc + (size_t)pg * CC;
    const float* shp = ssh + (size_t)pg * CC;
    float* op = out + (size_t)row * CC;
    #pragma unroll
    for (int q = 0; q < 4; q++) {
      int c = q * 256 + tid;
      float v = xb[(size_t)c * 49];
      op[c] = fmaxf(fmaf(v, scp[c], shp[c]), 0.f);
    }
  }
}

// ---------- weight/ctx pre-split into gload-ready interleaved hi/lo layout
// out row = 1024 u32: [slab 0..31][ 16 u32 hi pairs | 16 u32 lo pairs ]

__global__ void k_wsplit(const float* __restrict__ w, u32* __restrict__ dst, int total)
{
  int g = blockIdx.x * 256 + threadIdx.x;
  if (g >= total) return;
  int row = g >> 10;
  int rem = g & 1023;
  int slab = rem >> 5, j = rem & 31;
  int lo = j >> 4, jj = j & 15;
  const float* src = w + ((size_t)row << 10) + slab * 32 + 2 * jj;
  float f0 = src[0], f1 = src[1];
  u32 u0 = __float_as_uint(f0), u1 = __float_as_uint(f1);
  u32 v;
  if (lo == 0) {
    v = (u0 >> 16) | (u1 & 0xFFFF0000u);
  } else {
    float l0 = f0 - __uint_as_float(u0 & 0xFFFF0000u);
    float l1 = f1 - __uint_as_float(u1 & 0xFFFF0000u);
    v = (__float_as_uint(l0) >> 16) | (__float_as_uint(l1) & 0xFFFF0000u);
  }
  dst[g] = v;
}

// ------------------------------- BN3 affine + relu + 3x3 mean (vectorized)

__global__ void k_pool(const float* __restrict__ h, const float* __restrict__ ssc,
                       const float* __restrict__ ssh, float* __restrict__ apool,
                       int pbase)
{
  int row = blockIdx.x;                 // pl*256 + b
  int pl = row >> 8;
  int pg = pbase + pl;
  int c = threadIdx.x * 4;
  float4 sc = *(const float4*)(ssc + (size_t)pg * CC + c);
  float4 sh = *(const float4*)(ssh + (size_t)pg * CC + c);
  const float* hp = h + (size_t)row * 9 * CC + c;
  float4 s = {0.f, 0.f, 0.f, 0.f};
  #pragma unroll
  for (int yx = 0; yx < 9; yx++) {
    float4 v = *(const float4*)(hp + (size_t)yx * CC);
    s.x += fmaxf(fmaf(v.x, sc.x, sh.x), 0.f);
    s.y += fmaxf(fmaf(v.y, sc.y, sh.y), 0.f);
    s.z += fmaxf(fmaf(v.z, sc.z, sh.z), 0.f);
    s.w += fmaxf(fmaf(v.w, sc.w, sh.w), 0.f);
  }
  const float inv = 1.0f / 9.0f;
  float4 o = { s.x * inv, s.y * inv, s.z * inv, s.w * inv };
  *(float4*)(apool + (size_t)row * CC + c) = o;
}

// ------------------- finalize BN stats from per-mblock partials (18/patch)

__global__ void k_statsfin(const float* __restrict__ part, const float* __restrict__ gam,
                           const float* __restrict__ bet, float* __restrict__ ssc,
                           float* __restrict__ ssh, int pbase)
{
  int pl = blockIdx.x;
  int c  = blockIdx.y * 256 + threadIdx.x;
  float s1 = 0.f, s2 = 0.f;
  for (int mb = 0; mb < 18; mb++) {
    const float* pp = part + ((size_t)(pl * 18 + mb) * CC + c) * 2;
    s1 += pp[0]; s2 += pp[1];
  }
  const float inv = 1.0f / 2304.0f;
  float mean = s1 * inv;
  float var  = s2 * inv - mean * mean;
  float rs   = rsqrtf(var + EPS);
  float sc   = rs * gam[c];
  int pg = pbase + pl;
  ssc[(size_t)pg * CC + c] = sc;
  ssh[(size_t)pg * CC + c] = bet[c] - mean * sc;
}

// ------------------------------------------------------------ MFMA GEMM core
// C[m][n] = sum_k f(A[m][k]) * B[n][k] + bias[n]
// split-bf16: acc += ah*bh + al*bh + ah*bl  (fp32 MFMA accumulate)
// LDS layout per 128-row tile: row*32 u32, granule g (16B) at phys g^(row&7).
// MODE: 0 = A fp32 reg-staged, identity rows
//       1 = A fp32 reg-staged + BN affine/relu, identity rows
//       2 = A fp32 reg-staged + BN affine/relu, xt row-map (conv1)
//       3 = A pre-split, gload (heads)
// B always pre-split planes via global_load_lds.
// STATS: emit per-block column sum/sumsq to part[mb][col][2].

template<int MODE, bool STATS>
__device__ __forceinline__ void mg_body(
    const float* __restrict__ Af, const u32* __restrict__ Agl,
    const u32* __restrict__ Bp, const float* __restrict__ bias,
    float* __restrict__ Cmat, const float* __restrict__ ssc,
    const float* __restrict__ ssh, int pbase, int m0, int n0,
    float* __restrict__ part, int mb)
{
  __shared__ u32 sA[2][4096];
  __shared__ u32 sB[2][4096];
  __shared__ float sr1[4][64];
  __shared__ float sr2[4][64];

  const int t = threadIdx.x;
  const int l = t & 63, wv = t >> 6;
  const int lr = l & 15, lk = l >> 4;
  const int wm = (wv >> 1) * 64, wn = (wv & 1) * 64;

  // fragment read offsets (u32) with granule XOR swizzle
  int fAh[4], fAl[4], fBh[4], fBl[4];
  #pragma unroll
  for (int i = 0; i < 4; i++) {
    int Ra = wm + i * 16 + lr;
    int Rb = wn + i * 16 + lr;
    fAh[i] = Ra * 32 + ((lk ^ (Ra & 7)) << 2);
    fAl[i] = Ra * 32 + (((4 + lk) ^ (Ra & 7)) << 2);
    fBh[i] = Rb * 32 + ((lk ^ (Rb & 7)) << 2);
    fBl[i] = Rb * 32 + (((4 + lk) ^ (Rb & 7)) << 2);
  }

  // gload addressing: wave covers rows wv*32..wv*32+31 in 4 chunks of 8 rows
  int growq[4], ggq[4];
  #pragma unroll
  for (int q = 0; q < 4; q++) {
    int rr = wv * 32 + q * 8 + (l >> 3);
    growq[q] = rr;
    ggq[q] = (((l & 7) ^ (rr & 7)) << 2);
  }
  const u32* Brow = Bp + (size_t)n0 * 1024;
  const u32* Agr  = (MODE == 3) ? (Agl + (size_t)m0 * 1024) : nullptr;

  // reg-staging setup (MODE<3): thread = (row sr, 16-float half sh_)
  const int sr = t >> 1, sh_ = t & 1;
  const float *arow = nullptr, *scp = nullptr, *shp = nullptr;
  int wA[4] = {0, 0, 0, 0};
  if (MODE < 3) {
    wA[0] = sr * 32 + (((2 * sh_)     ^ (sr & 7)) << 2);
    wA[1] = sr * 32 + (((2 * sh_ + 1) ^ (sr & 7)) << 2);
    wA[2] = sr * 32 + (((4 + 2 * sh_) ^ (sr & 7)) << 2);
    wA[3] = sr * 32 + (((5 + 2 * sh_) ^ (sr & 7)) << 2);
    if (MODE == 2) {
      int pl = m0 / 2304, pg = pbase + pl;
      int q = m0 + sr - pl * 2304;
      int b = q / 9, yx = q % 9;
      int pos = (pg / 5 + yx / 3) * 7 + (pg % 5) + (yx % 3);
      arow = Af + ((size_t)b * 49 + pos) * CC + sh_ * 16;
      scp = ssc + (size_t)pg * CC + sh_ * 16;
      shp = ssh + (size_t)pg * CC + sh_ * 16;
    } else {
      arow = Af + (size_t)(m0 + sr) * CC + sh_ * 16;
      if (MODE == 1) {
        int pl = m0 / 2304, pg = pbase + pl;
        scp = ssc + (size_t)pg * CC + sh_ * 16;
        shp = ssh + (size_t)pg * CC + sh_ * 16;
      }
    }
  }

  f32x4 acc[4][4];
  #pragma unroll
  for (int i = 0; i < 4; i++)
    #pragma unroll
    for (int j = 0; j < 4; j++) { f32x4 z = {0.f, 0.f, 0.f, 0.f}; acc[i][j] = z; }

  float4 areg[4];

  // prologue: stage slab 0
  {
    int so = 0;
    #pragma unroll
    for (int q = 0; q < 4; q++)
      gload16(Brow + (size_t)growq[q] * 1024 + so + ggq[q],
              &sB[0][(wv * 32 + q * 8) * 32]);
    if (MODE == 3) {
      #pragma unroll
      for (int q = 0; q < 4; q++)
        gload16(Agr + (size_t)growq[q] * 1024 + so + ggq[q],
                &sA[0][(wv * 32 + q * 8) * 32]);
    } else {
      areg[0] = *(const float4*)(arow + 0);
      areg[1] = *(const float4*)(arow + 4);
      areg[2] = *(const float4*)(arow + 8);
      areg[3] = *(const float4*)(arow + 12);
      if (MODE == 1 || MODE == 2) {
        #pragma unroll
        for (int v = 0; v < 4; v++) {
          float4 s = *(const float4*)(scp + v * 4);
          float4 h = *(const float4*)(shp + v * 4);
          areg[v].x = fmaxf(fmaf(areg[v].x, s.x, h.x), 0.f);
          areg[v].y = fmaxf(fmaf(areg[v].y, s.y, h.y), 0.f);
          areg[v].z = fmaxf(fmaf(areg[v].z, s.z, h.z), 0.f);
          areg[v].w = fmaxf(fmaf(areg[v].w, s.w, h.w), 0.f);
        }
      }
      uint2 h0, l0, h1, l1, h2, l2, h3, l3;
      split_f4(areg[0], h0, l0); split_f4(areg[1], h1, l1);
      split_f4(areg[2], h2, l2); split_f4(areg[3], h3, l3);
      *(uint4*)&sA[0][wA[0]] = make_uint4(h0.x, h0.y, h1.x, h1.y);
      *(uint4*)&sA[0][wA[1]] = make_uint4(h2.x, h2.y, h3.x, h3.y);
      *(uint4*)&sA[0][wA[2]] = make_uint4(l0.x, l0.y, l1.x, l1.y);
      *(uint4*)&sA[0][wA[3]] = make_uint4(l2.x, l2.y, l3.x, l3.y);
    }
  }
  __syncthreads();

  #pragma unroll 1
  for (int it = 0; it < 32; ++it) {
    const int cur = it & 1, nxt = cur ^ 1;
    const int kk2 = (it + 1) << 5;
    const bool pf = (it < 31);
    if (pf) {
      int so = (kk2 >> 5) * 32;
      #pragma unroll
      for (int q = 0; q < 4; q++)
        gload16(Brow + (size_t)growq[q] * 1024 + so + ggq[q],
                &sB[nxt][(wv * 32 + q * 8) * 32]);
      if (MODE == 3) {
        #pragma unroll
        for (int q = 0; q < 4; q++)
          gload16(Agr + (size_t)growq[q] * 1024 + so + ggq[q],
                  &sA[nxt][(wv * 32 + q * 8) * 32]);
      } else {
        areg[0] = *(const float4*)(arow + kk2);
        areg[1] = *(const float4*)(arow + kk2 + 4);
        areg[2] = *(const float4*)(arow + kk2 + 8);
        areg[3] = *(const float4*)(arow + kk2 + 12);
      }
    }
    // compute on cur
    bf16x8 Ah[4], Al_[4], Bh[4], Bl[4];
    #pragma unroll
    for (int i = 0; i < 4; i++) {
      Ah[i]  = *(const bf16x8*)&sA[cur][fAh[i]];
      Al_[i] = *(const bf16x8*)&sA[cur][fAl[i]];
      Bh[i]  = *(const bf16x8*)&sB[cur][fBh[i]];
      Bl[i]  = *(const bf16x8*)&sB[cur][fBl[i]];
    }
    #pragma unroll
    for (int i = 0; i < 4; i++)
      #pragma unroll
      for (int j = 0; j < 4; j++) {
        acc[i][j] = MFMA16(Ah[i],  Bh[j], acc[i][j]);
        acc[i][j] = MFMA16(Al_[i], Bh[j], acc[i][j]);
        acc[i][j] = MFMA16(Ah[i],  Bl[j], acc[i][j]);
      }
    if (pf && MODE < 3) {
      if (MODE == 1 || MODE == 2) {
        #pragma unroll
        for (int v = 0; v < 4; v++) {
          float4 s = *(const float4*)(scp + kk2 + v * 4);
          float4 h = *(const float4*)(shp + kk2 + v * 4);
          areg[v].x = fmaxf(fmaf(areg[v].x, s.x, h.x), 0.f);
          areg[v].y = fmaxf(fmaf(areg[v].y, s.y, h.y), 0.f);
          areg[v].z = fmaxf(fmaf(areg[v].z, s.z, h.z), 0.f);
          areg[v].w = fmaxf(fmaf(areg[v].w, s.w, h.w), 0.f);
        }
      }
      uint2 h0, l0, h1, l1, h2, l2, h3, l3;
      split_f4(areg[0], h0, l0); split_f4(areg[1], h1, l1);
      split_f4(areg[2], h2, l2); split_f4(areg[3], h3, l3);
      *(uint4*)&sA[nxt][wA[0]] = make_uint4(h0.x, h0.y, h1.x, h1.y);
      *(uint4*)&sA[nxt][wA[1]] = make_uint4(h2.x, h2.y, h3.x, h3.y);
      *(uint4*)&sA[nxt][wA[2]] = make_uint4(l0.x, l0.y, l1.x, l1.y);
      *(uint4*)&sA[nxt][wA[3]] = make_uint4(l2.x, l2.y, l3.x, l3.y);
    }
    __syncthreads();
  }

  // epilogue: D row = lk*4 + reg, col = lr [m89 layout]; optional col stats
  float st1[4], st2[4];
  #pragma unroll
  for (int j = 0; j < 4; j++) { st1[j] = 0.f; st2[j] = 0.f; }
  #pragma unroll
  for (int j = 0; j < 4; j++) {
    int ocol = n0 + wn + j * 16 + lr;
    float bj = bias[ocol];
    #pragma unroll
    for (int i = 0; i < 4; i++) {
      int orow = m0 + wm + i * 16 + lk * 4;
      float* cp = Cmat + (size_t)orow * CC + ocol;
      #pragma unroll
      for (int reg = 0; reg < 4; reg++) {
        float v = acc[i][j][reg] + bj;
        cp[(size_t)reg * CC] = v;
        if (STATS) { st1[j] += v; st2[j] = fmaf(v, v, st2[j]); }
      }
    }
  }
  if (STATS) {
    #pragma unroll
    for (int j = 0; j < 4; j++) {
      st1[j] += __shfl_xor(st1[j], 16, 64);
      st1[j] += __shfl_xor(st1[j], 32, 64);
      st2[j] += __shfl_xor(st2[j], 16, 64);
      st2[j] += __shfl_xor(st2[j], 32, 64);
    }
    if (lk == 0) {
      #pragma unroll
      for (int j = 0; j < 4; j++) {
        sr1[wv][j * 16 + lr] = st1[j];
        sr2[wv][j * 16 + lr] = st2[j];
      }
    }
    __syncthreads();
    if (t < 128) {
      int ch = t >> 6, c6 = t & 63;
      float a1 = sr1[ch][c6] + sr1[ch + 2][c6];
      float a2 = sr2[ch][c6] + sr2[ch + 2][c6];
      float2 o = { a1, a2 };
      *(float2*)(part + ((size_t)mb * CC + n0 + t) * 2) = o;
    }
  }
}

template<int MODE, bool STATS>
__global__ __launch_bounds__(256, 2)
void k_mg(const float* __restrict__ Af, const u32* __restrict__ Bp,
          const float* __restrict__ bias, float* __restrict__ Cmat,
          const float* __restrict__ ssc, const float* __restrict__ ssh,
          int pbase, float* __restrict__ part)
{
  mg_body<MODE, STATS>(Af, nullptr, Bp, bias, Cmat, ssc, ssh, pbase,
                       blockIdx.x * 128, blockIdx.y * 128, part, blockIdx.x);
}

template<int MODE>
__global__ __launch_bounds__(256, 2)
void k_heads(const float* __restrict__ ctx, const u32* __restrict__ ctxp,
             const u32* __restrict__ wplh, const float* __restrict__ lb,
             float* __restrict__ out)
{
  int p, w;
  head_entry(blockIdx.y, &p, &w);
  mg_body<MODE, false>(ctx + (size_t)p * BB * CC,
                       ctxp ? ctxp + (size_t)p * BB * 1024 : nullptr,
                       wplh + (size_t)w * 1048576,
                       lb + (size_t)w * CC,
                       out + (size_t)blockIdx.y * BB * CC,
                       nullptr, nullptr, 0,
                       (blockIdx.x >> 3) * 128, (blockIdx.x & 7) * 128,
                       nullptr, 0);
}

// ---------------------------------------------------------------- launch

extern "C" void kernel_launch(void* const* d_in, const int* in_sizes, int n_in,
                              void* d_out, int out_size, void* d_ws, size_t ws_size,
                              hipStream_t stream)
{
  const float* x   = (const float*)d_in[0];
  const float* bng = (const float*)d_in[1];
  const float* bnb = (const float*)d_in[2];
  const float* cw  = (const float*)d_in[3];
  const float* cb  = (const float*)d_in[4];
  const float* lw  = (const float*)d_in[5];
  const float* lb  = (const float*)d_in[6];
  float* out = (float*)d_out;
  float* ws  = (float*)d_ws;

  const size_t W = ws_size / 4;           // 4-byte words
  const size_t SZ_WPL = 15ull * 1048576;
  const size_t SZ_XT  = 256ull * 49 * 1024;
  const size_t SZ_G   = 2304ull * 1024;
  const size_t SZ_CTX = 6400ull * 1024;
  const size_t SZ_XS  = 50176;
  const size_t SZ_SS  = 25ull * 1024;

  auto need = [&](int PC, bool xt, bool cp) -> size_t {
    size_t Mc = (size_t)PC * 2304;
    return SZ_WPL + (xt ? SZ_XT : SZ_G) + 2 * Mc * 1024
         + (size_t)PC * 256 * 1024 + SZ_CTX + 2 * SZ_XS + 2 * SZ_SS
         + (Mc / 128) * 1024 * 2 + (cp ? SZ_CTX : 0);
  };
  int PC; bool useXT, useCP;
  if      (W >= need(5, true, true))  { PC = 5; useXT = true;  useCP = true;  }
  else if (W >= need(5, true, false)) { PC = 5; useXT = true;  useCP = false; }
  else if (W >= need(1, true, false)) { PC = 1; useXT = true;  useCP = false; }
  else                                { PC = 1; useXT = false; useCP = false; }

  const int NCH = NP / PC;
  const size_t Mc = (size_t)PC * 2304;

  u32*   wpl    = (u32*)ws;
  float* xtg    = (float*)(wpl + SZ_WPL);       // xt (or gather buf in low tier)
  float* h1     = xtg + (useXT ? SZ_XT : SZ_G);
  float* h2     = h1 + Mc * 1024;
  float* pooled = h2 + Mc * 1024;
  float* ctx    = pooled + (size_t)PC * 256 * 1024;
  float* xs1    = ctx + SZ_CTX;
  float* xs2    = xs1 + SZ_XS;
  float* ssc    = xs2 + SZ_XS;
  float* ssh    = ssc + SZ_SS;
  float* part   = ssh + SZ_SS;
  u32*   ctxp   = (u32*)(part + (Mc / 128) * 1024 * 2);

  // pre-split all 15 weight matrices into gload layout
  k_wsplit<<<(3 * 1048576) / 256, 256, 0, stream>>>(cw, wpl, 3 * 1048576);
  k_wsplit<<<(12 * 1048576) / 256, 256, 0, stream>>>(lw, wpl + 3ull * 1048576,
                                                     12 * 1048576);
  if (useXT) k_transpose<<<dim3(256, 8), 256, 0, stream>>>(x, xtg);
  k_xsums<<<196, 256, 0, stream>>>(x, xs1, xs2);
  k_stats1<<<dim3(25, 4), 256, 0, stream>>>(xs1, xs2, bng, bnb, ssc, ssh);

  const dim3 gconv((int)(Mc / 128), 8);
  const dim3 gp3((int)(PC * 256 / 128), 8);

  for (int ch = 0; ch < NCH; ++ch) {
    const int pbase = ch * PC;
    if (useXT) {
      k_mg<2, true><<<gconv, 256, 0, stream>>>(xtg, wpl, cb, h1, ssc, ssh, pbase, part);
    } else {
      k_gather<<<(int)(Mc / 16), 256, 0, stream>>>(x, ssc, ssh, xtg, pbase);
      k_mg<0, true><<<gconv, 256, 0, stream>>>(xtg, wpl, cb, h1, ssc, ssh, pbase, part);
    }
    k_statsfin<<<dim3(PC, 4), 256, 0, stream>>>(part, bng + CC, bnb + CC, ssc, ssh, pbase);
    k_mg<1, true><<<gconv, 256, 0, stream>>>(h1, wpl + 1ull * 1048576, cb + CC,
                                             h2, ssc, ssh, pbase, part);
    k_statsfin<<<dim3(PC, 4), 256, 0, stream>>>(part, bng + 2 * CC, bnb + 2 * CC, ssc, ssh, pbase);
    k_pool<<<PC * 256, 256, 0, stream>>>(h2, ssc, ssh, pooled, pbase);
    k_mg<0, false><<<gp3, 256, 0, stream>>>(pooled, wpl + 2ull * 1048576, cb + 2 * CC,
                                            ctx + (size_t)pbase * 256 * CC,
                                            nullptr, nullptr, 0, nullptr);
  }

  if (useCP) {
    k_wsplit<<<(6400 * 1024) / 256, 256, 0, stream>>>(ctx, ctxp, 6400 * 1024);
    k_heads<3><<<dim3(16, 120), 256, 0, stream>>>(ctx, ctxp, wpl + 3ull * 1048576, lb, out);
  } else {
    k_heads<0><<<dim3(16, 120), 256, 0, stream>>>(ctx, nullptr, wpl + 3ull * 1048576, lb, out);
  }
}